// Round 2
// baseline (349.413 us; speedup 1.0000x reference)
//
#include <hip/hip_runtime.h>

// S = 256. Out[b][D][q] = sum_k softmax_k(QK^T/16)[b,q,k]*keep[b,q,k]*v[b,k,D]
// qk_bias is a per-(b,q) additive constant before softmax -> softmax-invariant -> skipped.
// d_ws holds vT[b][D][k] as bf16: 256^3 * 2 = 33,554,432 bytes.
//
// Round-4 structure (occupancy round): attn_kernel was latency-bound at
// 18.6% occupancy (LDS 50.7 KB -> 3 blocks/CU vs grid need of 4). Changes:
//  * single 33.8 KB LDS buffer time-shared: K slabs -> P -> vT slabs
//    (each wave register-caches its 16 P-rows as pf[] before the overlay)
//    -> 4 blocks/CU fully resident (__launch_bounds__(256,4)).
//  * dropout applied in-register in the pf fragment layout, reading drop_u
//    directly at (q0+lid, k0*32+quad*8); removes ur[16] (64 VGPRs) and the
//    in-LDS RMW pass + one barrier. Same bf16 rounding points as before.
//  * phase B: 8 slabs of 32 D-rows (2 MFMA chains/slab), half the barriers,
//    per-slab streaming stores (no 64-reg oacc held to an epilogue).
// (Round-5 resubmit: round-4 bench was an infra failure, kernel unmeasured.)

#define SDIM 256
#define LDSP 264  // padded LDS row stride (elements); 264*2=528B, 16B-aligned

typedef __bf16 bf16_t;
typedef __bf16 bf16x8 __attribute__((ext_vector_type(8)));
typedef __bf16 bf16x4 __attribute__((ext_vector_type(4)));
typedef float f32x4 __attribute__((ext_vector_type(4)));

__device__ inline bf16x8 cvt8(float4 a, float4 b) {
  bf16x8 r;
  r[0] = (bf16_t)a.x; r[1] = (bf16_t)a.y; r[2] = (bf16_t)a.z; r[3] = (bf16_t)a.w;
  r[4] = (bf16_t)b.x; r[5] = (bf16_t)b.y; r[6] = (bf16_t)b.z; r[7] = (bf16_t)b.w;
  return r;
}
__device__ inline bf16x4 cvt4(float4 a) {
  bf16x4 r;
  r[0] = (bf16_t)a.x; r[1] = (bf16_t)a.y; r[2] = (bf16_t)a.z; r[3] = (bf16_t)a.w;
  return r;
}

// ---------------------------------------------------------------------------
// Kernel 1: vT[b][D][k] = sum_d W[b][d][D]*value[b][k][d] + v_bias[k][D], bf16
// grid = 1024 (XCD-swizzled (b, Dblk)); block = 256 (4 waves).  UNCHANGED.
// ---------------------------------------------------------------------------
__global__ __launch_bounds__(256) void vproj_kernel(
    const float* __restrict__ value, const float* __restrict__ v_weight,
    const float* __restrict__ v_bias, bf16_t* __restrict__ vT)
{
  __shared__ bf16_t SH[64 * LDSP];

  // XCD swizzle: all 4 Dblks of a given b share xcd = b & 7.
  const int pidx = blockIdx.x;
  const int xcd  = pidx & 7;
  const int jj   = pidx >> 3;
  const int Dblk = jj & 3;
  const int b    = xcd + ((jj >> 2) << 3);
  const int Dbase = Dblk * 64;

  const int t    = threadIdx.x;
  const int w    = t >> 6;
  const int lane = t & 63;
  const int lid  = lane & 15;
  const int quad = lane >> 4;

  const float* Wb = v_weight + (size_t)b * (SDIM * SDIM);
  const float* Vb = value    + (size_t)b * (SDIM * SDIM);

  // Issue slab-0 value loads first (in flight during WT staging).
  float4 vr[8];
  #pragma unroll
  for (int p2 = 0; p2 < 8; ++p2)
    vr[p2] = *(const float4*)(Vb + (p2 * 4 + w) * SDIM + lane * 4);

  // Bias preload (scattered, hidden behind the GEMM).
  bf16x4 biasr[16];
  {
    const float* bp = v_bias + Dbase + w * 16 + quad * 4;
    #pragma unroll
    for (int n = 0; n < 16; ++n)
      biasr[n] = cvt4(*(const float4*)(bp + (n * 16 + lid) * SDIM));
  }

  // Stage W^T tile (bf16) into SH; cache A-fragments in registers.
  {
    const int c4 = (t & 15) * 4;
    const int r0 = t >> 4;
    #pragma unroll
    for (int p = 0; p < 16; ++p) {
      const int r = p * 16 + r0;
      float4 f = *(const float4*)(Wb + r * SDIM + Dbase + c4);
      SH[(c4 + 0) * LDSP + r] = (bf16_t)f.x;
      SH[(c4 + 1) * LDSP + r] = (bf16_t)f.y;
      SH[(c4 + 2) * LDSP + r] = (bf16_t)f.z;
      SH[(c4 + 3) * LDSP + r] = (bf16_t)f.w;
    }
  }
  __syncthreads();
  bf16x8 af[8];
  #pragma unroll
  for (int d = 0; d < 8; ++d)
    af[d] = *(const bf16x8*)(&SH[(w * 16 + lid) * LDSP + d * 32 + quad * 8]);
  __syncthreads();  // all waves read WT before value slabs overwrite SH

  // Write slab 0 into buffer 0.
  #pragma unroll
  for (int p2 = 0; p2 < 8; ++p2)
    *(bf16x4*)(&SH[(p2 * 4 + w) * LDSP + lane * 4]) = cvt4(vr[p2]);

  f32x4 acc[16];
  #pragma unroll
  for (int n = 0; n < 16; ++n) acc[n] = (f32x4){0.f, 0.f, 0.f, 0.f};

  // Pipelined K-loop: 8 slabs of 32 k-rows, double-buffered in SH halves.
  for (int s = 0; s < 8; ++s) {
    if (s < 7) {
      #pragma unroll
      for (int p2 = 0; p2 < 8; ++p2)
        vr[p2] = *(const float4*)(Vb + ((s + 1) * 32 + p2 * 4 + w) * SDIM + lane * 4);
    }
    __syncthreads();  // buffer s&1 ready; prior readers of buffer (s+1)&1 done
    const int rb = (s & 1) * 32;
    #pragma unroll
    for (int n4 = 0; n4 < 2; ++n4) {
      const int n = s * 2 + n4;
      #pragma unroll
      for (int d = 0; d < 8; ++d) {
        bf16x8 bfr = *(const bf16x8*)(&SH[(rb + n4 * 16 + lid) * LDSP + d * 32 + quad * 8]);
        acc[n] = __builtin_amdgcn_mfma_f32_16x16x32_bf16(af[d], bfr, acc[n], 0, 0, 0);
      }
    }
    if (s < 7) {
      const int wb = ((s + 1) & 1) * 32;
      #pragma unroll
      for (int p2 = 0; p2 < 8; ++p2)
        *(bf16x4*)(&SH[(wb + p2 * 4 + w) * LDSP + lane * 4]) = cvt4(vr[p2]);
    }
  }
  __syncthreads();

  // Epilogue: add bias, bounce via SH, full-line coalesced stores.
  #pragma unroll
  for (int n = 0; n < 16; ++n) {
    const int k = n * 16 + lid;
    #pragma unroll
    for (int j = 0; j < 4; ++j) {
      const int Dloc = w * 16 + quad * 4 + j;
      SH[Dloc * LDSP + k] = (bf16_t)(acc[n][j] + (float)biasr[n][j]);
    }
  }
  __syncthreads();
  bf16_t* outb = vT + (size_t)b * (SDIM * SDIM) + (size_t)Dbase * SDIM;
  #pragma unroll
  for (int p = 0; p < 8; ++p) {
    const int r = p * 8 + (t >> 5);
    const int c = (t & 31) * 8;
    bf16x8 h = *(const bf16x8*)(&SH[r * LDSP + c]);
    *(bf16x8*)(outb + r * SDIM + c) = h;
  }
}

// ---------------------------------------------------------------------------
// Kernel 2: fused attention. grid = 1024 (XCD-swizzled (b, qt)); block = 256.
// One 33.8 KB LDS buffer time-shared across phases -> 4 blocks/CU resident.
// ---------------------------------------------------------------------------
__global__ __launch_bounds__(256, 4) void attn_kernel(
    const float* __restrict__ query, const float* __restrict__ key,
    const float* __restrict__ drop_u, const bf16_t* __restrict__ vT,
    float* __restrict__ out)
{
  // phase A: K slabs (2 x 32 rows, double-buffered)
  // middle : P (64 q-rows x 256 k)
  // phase B: vT slabs (2 x 32 rows) -- safe: every wave caches its 16 P-rows
  //          in pf[] registers before the overlay barrier.
  __shared__ bf16_t KP[64 * LDSP];

  const int pidx = blockIdx.x;
  const int xcd  = pidx & 7;
  const int jj   = pidx >> 3;
  const int qt   = jj & 3;
  const int b    = xcd + ((jj >> 2) << 3);

  const int t    = threadIdx.x;
  const int w    = t >> 6;
  const int lane = t & 63;
  const int lid  = lane & 15;
  const int quad = lane >> 4;
  const int q0   = qt * 64 + w * 16;

  const float* Qb = query + (size_t)b * (SDIM * SDIM);
  const float* Kb = key   + (size_t)b * (SDIM * SDIM);

  // Issue K slab-0 loads first.
  float4 kr[8];
  #pragma unroll
  for (int p2 = 0; p2 < 8; ++p2)
    kr[p2] = *(const float4*)(Kb + (p2 * 4 + w) * SDIM + lane * 4);

  // Q fragments (A-layout: row = q0+lid, k = d*32 + quad*8 + j).
  bf16x8 qf[8];
  #pragma unroll
  for (int d = 0; d < 8; ++d) {
    const float* p = Qb + (q0 + lid) * SDIM + d * 32 + quad * 8;
    float4 a = *(const float4*)(p);
    float4 c = *(const float4*)(p + 4);
    qf[d] = cvt8(a, c);
  }

  // Write slab 0 into KP buffer 0.
  #pragma unroll
  for (int p2 = 0; p2 < 8; ++p2)
    *(bf16x4*)(&KP[(p2 * 4 + w) * LDSP + lane * 4]) = cvt4(kr[p2]);

  f32x4 sacc[16];
  #pragma unroll
  for (int n = 0; n < 16; ++n) sacc[n] = (f32x4){0.f, 0.f, 0.f, 0.f};

  // Phase A: pipelined over 8 slabs of 32 key rows.
  #pragma unroll
  for (int s = 0; s < 8; ++s) {
    if (s < 7) {
      #pragma unroll
      for (int p2 = 0; p2 < 8; ++p2)
        kr[p2] = *(const float4*)(Kb + ((s + 1) * 32 + p2 * 4 + w) * SDIM + lane * 4);
    }
    __syncthreads();
    const int rb = (s & 1) * 32;
    #pragma unroll
    for (int n4 = 0; n4 < 2; ++n4) {
      const int n = s * 2 + n4;
      #pragma unroll
      for (int d = 0; d < 8; ++d) {
        bf16x8 bfr = *(const bf16x8*)(&KP[(rb + n4 * 16 + lid) * LDSP + d * 32 + quad * 8]);
        sacc[n] = __builtin_amdgcn_mfma_f32_16x16x32_bf16(qf[d], bfr, sacc[n], 0, 0, 0);
      }
    }
    if (s < 7) {
      const int wb = ((s + 1) & 1) * 32;
      #pragma unroll
      for (int p2 = 0; p2 < 8; ++p2)
        *(bf16x4*)(&KP[(wb + p2 * 4 + w) * LDSP + lane * 4]) = cvt4(kr[p2]);
    }
  }
  __syncthreads();  // phase A reads done; KP free for P

  // Softmax per q-row (C-layout: q = quad*4+j, key = n*16+lid).
  #pragma unroll
  for (int j = 0; j < 4; ++j) {
    float mx = sacc[0][j];
    #pragma unroll
    for (int n = 1; n < 16; ++n) mx = fmaxf(mx, sacc[n][j]);
    #pragma unroll
    for (int off = 8; off >= 1; off >>= 1) mx = fmaxf(mx, __shfl_xor(mx, off, 64));
    float sum = 0.f;
    #pragma unroll
    for (int n = 0; n < 16; ++n) {
      float e = __expf((sacc[n][j] - mx) * 0.0625f);
      sacc[n][j] = e;
      sum += e;
    }
    #pragma unroll
    for (int off = 8; off >= 1; off >>= 1) sum += __shfl_xor(sum, off, 64);
    float inv = 1.0f / sum;
    #pragma unroll
    for (int n = 0; n < 16; ++n) sacc[n][j] *= inv;
  }

  // Write P (pre-dropout) to KP rows = q-within-tile.
  #pragma unroll
  for (int n = 0; n < 16; ++n) {
    #pragma unroll
    for (int j = 0; j < 4; ++j)
      KP[(w * 16 + quad * 4 + j) * LDSP + n * 16 + lid] = (bf16_t)sacc[n][j];
  }
  __syncthreads();

  // Cache P fragments (B-layout: q-row = w*16+lid, k = k0*32 + quad*8 + j),
  // then apply dropout in-register: drop_u is read directly in this layout
  // (per lane 2xfloat4 per k0; the k0 loop consumes full 128B lines).
  bf16x8 pf[8];
  #pragma unroll
  for (int k0 = 0; k0 < 8; ++k0)
    pf[k0] = *(const bf16x8*)(&KP[(w * 16 + lid) * LDSP + k0 * 32 + quad * 8]);

  {
    const float* Ub = drop_u + (size_t)b * (SDIM * SDIM) + (size_t)(q0 + lid) * SDIM + quad * 8;
    const float rs = 1.0f / 0.9f;
    #pragma unroll
    for (int k0 = 0; k0 < 8; ++k0) {
      float4 u0 = *(const float4*)(Ub + k0 * 32);
      float4 u1 = *(const float4*)(Ub + k0 * 32 + 4);
      pf[k0][0] = (u0.x >= 0.1f) ? (bf16_t)((float)pf[k0][0] * rs) : (bf16_t)0.f;
      pf[k0][1] = (u0.y >= 0.1f) ? (bf16_t)((float)pf[k0][1] * rs) : (bf16_t)0.f;
      pf[k0][2] = (u0.z >= 0.1f) ? (bf16_t)((float)pf[k0][2] * rs) : (bf16_t)0.f;
      pf[k0][3] = (u0.w >= 0.1f) ? (bf16_t)((float)pf[k0][3] * rs) : (bf16_t)0.f;
      pf[k0][4] = (u1.x >= 0.1f) ? (bf16_t)((float)pf[k0][4] * rs) : (bf16_t)0.f;
      pf[k0][5] = (u1.y >= 0.1f) ? (bf16_t)((float)pf[k0][5] * rs) : (bf16_t)0.f;
      pf[k0][6] = (u1.z >= 0.1f) ? (bf16_t)((float)pf[k0][6] * rs) : (bf16_t)0.f;
      pf[k0][7] = (u1.w >= 0.1f) ? (bf16_t)((float)pf[k0][7] * rs) : (bf16_t)0.f;
    }
  }

  // Phase B prologue: issue vT slab-0 loads (regs only), then overlay barrier.
  const bf16_t* vTb = vT + (size_t)b * (SDIM * SDIM);
  float* outbp = out + (size_t)b * (SDIM * SDIM);

  bf16x8 tr[4];
  #pragma unroll
  for (int p3 = 0; p3 < 4; ++p3)
    tr[p3] = *(const bf16x8*)(vTb + (p3 * 8 + (t >> 5)) * SDIM + (t & 31) * 8);

  __syncthreads();  // all pf reads of KP complete; KP free for vT slabs

  #pragma unroll
  for (int p3 = 0; p3 < 4; ++p3)
    *(bf16x8*)(&KP[(p3 * 8 + (t >> 5)) * LDSP + (t & 31) * 8]) = tr[p3];

  // Phase B: 8 slabs of 32 vT D-rows, double-buffered in KP halves.
  // out^T[D][q] = vT * P^T; per-slab streaming stores.
  #pragma unroll
  for (int s = 0; s < 8; ++s) {
    if (s < 7) {
      #pragma unroll
      for (int p3 = 0; p3 < 4; ++p3)
        tr[p3] = *(const bf16x8*)(vTb + ((s + 1) * 32 + p3 * 8 + (t >> 5)) * SDIM + (t & 31) * 8);
    }
    __syncthreads();  // buffer s&1 ready; prior readers of buffer (s+1)&1 done
    const int rb = (s & 1) * 32;
    f32x4 o0 = (f32x4){0.f, 0.f, 0.f, 0.f};
    f32x4 o1 = (f32x4){0.f, 0.f, 0.f, 0.f};
    #pragma unroll
    for (int k0 = 0; k0 < 8; ++k0) {
      bf16x8 a0 = *(const bf16x8*)(&KP[(rb + lid) * LDSP + k0 * 32 + quad * 8]);
      bf16x8 a1 = *(const bf16x8*)(&KP[(rb + 16 + lid) * LDSP + k0 * 32 + quad * 8]);
      o0 = __builtin_amdgcn_mfma_f32_16x16x32_bf16(a0, pf[k0], o0, 0, 0, 0);
      o1 = __builtin_amdgcn_mfma_f32_16x16x32_bf16(a1, pf[k0], o1, 0, 0, 0);
    }
    if (s < 7) {
      const int wb = ((s + 1) & 1) * 32;
      #pragma unroll
      for (int p3 = 0; p3 < 4; ++p3)
        *(bf16x8*)(&KP[(wb + p3 * 8 + (t >> 5)) * LDSP + (t & 31) * 8]) = tr[p3];
    }
    #pragma unroll
    for (int j = 0; j < 4; ++j) {
      outbp[(s * 32 + quad * 4 + j) * SDIM + q0 + lid] = o0[j];
      outbp[(s * 32 + 16 + quad * 4 + j) * SDIM + q0 + lid] = o1[j];
    }
  }
}

extern "C" void kernel_launch(void* const* d_in, const int* in_sizes, int n_in,
                              void* d_out, int out_size, void* d_ws, size_t ws_size,
                              hipStream_t stream) {
  (void)in_sizes; (void)n_in; (void)out_size; (void)ws_size;
  const float* query    = (const float*)d_in[0];
  const float* key      = (const float*)d_in[1];
  const float* value    = (const float*)d_in[2];
  const float* drop_u   = (const float*)d_in[3];
  // d_in[4] = qk_bias: softmax-invariant -> skipped.
  const float* v_weight = (const float*)d_in[5];
  const float* v_bias   = (const float*)d_in[6];
  float* out = (float*)d_out;
  bf16_t* vT = (bf16_t*)d_ws;  // 33,554,432 bytes of workspace

  vproj_kernel<<<dim3(1024), dim3(256), 0, stream>>>(value, v_weight, v_bias, vT);
  attn_kernel<<<dim3(1024), dim3(256), 0, stream>>>(query, key, drop_u, vT, out);
}

// Round 3
// 347.300 us; speedup vs baseline: 1.0061x; 1.0061x over previous
//
#include <hip/hip_runtime.h>

// S = 256. Out[b][D][q] = sum_k softmax_k(QK^T/16)[b,q,k]*keep[b,q,k]*v[b,k,D]
// qk_bias is a per-(b,q) additive constant before softmax -> softmax-invariant -> skipped.
// d_ws holds vT[b][D][k] as bf16: 256^3 * 2 = 33,554,432 bytes.
//
// Round-6: barrier-drain fix. rocprof showed occupancy doubling (18->38%) with
// zero time change: every pipe idle ~70%. Cause: __syncthreads() drains
// vmcnt(0) (compiler emits s_waitcnt vmcnt(0) before s_barrier), so the
// register-destination prefetch loads issued just before each barrier are
// fully drained AT the barrier -- the "pipeline" had zero memory/compute
// overlap. The loads crossing the barrier are per-wave register loads that
// need no barrier ordering; only LDS ops do. Fix: bar_lds() = s_waitcnt
// lgkmcnt(0) + raw s_barrier (m201-verified plain-HIP pattern), leaving
// global loads in flight across the barrier. Consume-side sync is the
// compiler's automatic vmcnt(N) waits at the kr/tr/vr uses.

#define SDIM 256
#define LDSP 264  // padded LDS row stride (elements); 264*2=528B, 16B-aligned

typedef __bf16 bf16_t;
typedef __bf16 bf16x8 __attribute__((ext_vector_type(8)));
typedef __bf16 bf16x4 __attribute__((ext_vector_type(4)));
typedef float f32x4 __attribute__((ext_vector_type(4)));

// Workgroup barrier that orders LDS ops only: does NOT drain vmcnt, so
// register-destination global loads stay in flight across it. All
// cross-barrier hazards in these kernels are LDS-only.
__device__ inline void bar_lds() {
  asm volatile("s_waitcnt lgkmcnt(0)" ::: "memory");
  __builtin_amdgcn_s_barrier();
}

__device__ inline bf16x8 cvt8(float4 a, float4 b) {
  bf16x8 r;
  r[0] = (bf16_t)a.x; r[1] = (bf16_t)a.y; r[2] = (bf16_t)a.z; r[3] = (bf16_t)a.w;
  r[4] = (bf16_t)b.x; r[5] = (bf16_t)b.y; r[6] = (bf16_t)b.z; r[7] = (bf16_t)b.w;
  return r;
}
__device__ inline bf16x4 cvt4(float4 a) {
  bf16x4 r;
  r[0] = (bf16_t)a.x; r[1] = (bf16_t)a.y; r[2] = (bf16_t)a.z; r[3] = (bf16_t)a.w;
  return r;
}

// ---------------------------------------------------------------------------
// Kernel 1: vT[b][D][k] = sum_d W[b][d][D]*value[b][k][d] + v_bias[k][D], bf16
// grid = 1024 (XCD-swizzled (b, Dblk)); block = 256 (4 waves).
// ---------------------------------------------------------------------------
__global__ __launch_bounds__(256) void vproj_kernel(
    const float* __restrict__ value, const float* __restrict__ v_weight,
    const float* __restrict__ v_bias, bf16_t* __restrict__ vT)
{
  __shared__ bf16_t SH[64 * LDSP];

  // XCD swizzle: all 4 Dblks of a given b share xcd = b & 7.
  const int pidx = blockIdx.x;
  const int xcd  = pidx & 7;
  const int jj   = pidx >> 3;
  const int Dblk = jj & 3;
  const int b    = xcd + ((jj >> 2) << 3);
  const int Dbase = Dblk * 64;

  const int t    = threadIdx.x;
  const int w    = t >> 6;
  const int lane = t & 63;
  const int lid  = lane & 15;
  const int quad = lane >> 4;

  const float* Wb = v_weight + (size_t)b * (SDIM * SDIM);
  const float* Vb = value    + (size_t)b * (SDIM * SDIM);

  // Issue slab-0 value loads first (in flight during WT staging).
  float4 vr[8];
  #pragma unroll
  for (int p2 = 0; p2 < 8; ++p2)
    vr[p2] = *(const float4*)(Vb + (p2 * 4 + w) * SDIM + lane * 4);

  // Bias preload (scattered, hidden behind the GEMM).
  bf16x4 biasr[16];
  {
    const float* bp = v_bias + Dbase + w * 16 + quad * 4;
    #pragma unroll
    for (int n = 0; n < 16; ++n)
      biasr[n] = cvt4(*(const float4*)(bp + (n * 16 + lid) * SDIM));
  }

  // Stage W^T tile (bf16) into SH; cache A-fragments in registers.
  {
    const int c4 = (t & 15) * 4;
    const int r0 = t >> 4;
    #pragma unroll
    for (int p = 0; p < 16; ++p) {
      const int r = p * 16 + r0;
      float4 f = *(const float4*)(Wb + r * SDIM + Dbase + c4);
      SH[(c4 + 0) * LDSP + r] = (bf16_t)f.x;
      SH[(c4 + 1) * LDSP + r] = (bf16_t)f.y;
      SH[(c4 + 2) * LDSP + r] = (bf16_t)f.z;
      SH[(c4 + 3) * LDSP + r] = (bf16_t)f.w;
    }
  }
  bar_lds();
  bf16x8 af[8];
  #pragma unroll
  for (int d = 0; d < 8; ++d)
    af[d] = *(const bf16x8*)(&SH[(w * 16 + lid) * LDSP + d * 32 + quad * 8]);
  bar_lds();  // all waves read WT before value slabs overwrite SH

  // Write slab 0 into buffer 0.
  #pragma unroll
  for (int p2 = 0; p2 < 8; ++p2)
    *(bf16x4*)(&SH[(p2 * 4 + w) * LDSP + lane * 4]) = cvt4(vr[p2]);

  f32x4 acc[16];
  #pragma unroll
  for (int n = 0; n < 16; ++n) acc[n] = (f32x4){0.f, 0.f, 0.f, 0.f};

  // Pipelined K-loop: 8 slabs of 32 k-rows, double-buffered in SH halves.
  #pragma unroll
  for (int s = 0; s < 8; ++s) {
    if (s < 7) {
      #pragma unroll
      for (int p2 = 0; p2 < 8; ++p2)
        vr[p2] = *(const float4*)(Vb + ((s + 1) * 32 + p2 * 4 + w) * SDIM + lane * 4);
    }
    bar_lds();  // buffer s&1 ready; prior readers of buffer (s+1)&1 done
    const int rb = (s & 1) * 32;
    #pragma unroll
    for (int n4 = 0; n4 < 2; ++n4) {
      const int n = s * 2 + n4;
      #pragma unroll
      for (int d = 0; d < 8; ++d) {
        bf16x8 bfr = *(const bf16x8*)(&SH[(rb + n4 * 16 + lid) * LDSP + d * 32 + quad * 8]);
        acc[n] = __builtin_amdgcn_mfma_f32_16x16x32_bf16(af[d], bfr, acc[n], 0, 0, 0);
      }
    }
    if (s < 7) {
      const int wb = ((s + 1) & 1) * 32;
      #pragma unroll
      for (int p2 = 0; p2 < 8; ++p2)
        *(bf16x4*)(&SH[(wb + p2 * 4 + w) * LDSP + lane * 4]) = cvt4(vr[p2]);
    }
  }
  bar_lds();

  // Epilogue: add bias, bounce via SH, full-line coalesced stores.
  #pragma unroll
  for (int n = 0; n < 16; ++n) {
    const int k = n * 16 + lid;
    #pragma unroll
    for (int j = 0; j < 4; ++j) {
      const int Dloc = w * 16 + quad * 4 + j;
      SH[Dloc * LDSP + k] = (bf16_t)(acc[n][j] + (float)biasr[n][j]);
    }
  }
  bar_lds();
  bf16_t* outb = vT + (size_t)b * (SDIM * SDIM) + (size_t)Dbase * SDIM;
  #pragma unroll
  for (int p = 0; p < 8; ++p) {
    const int r = p * 8 + (t >> 5);
    const int c = (t & 31) * 8;
    bf16x8 h = *(const bf16x8*)(&SH[r * LDSP + c]);
    *(bf16x8*)(outb + r * SDIM + c) = h;
  }
}

// ---------------------------------------------------------------------------
// Kernel 2: fused attention. grid = 1024 (XCD-swizzled (b, qt)); block = 256.
// One 33.8 KB LDS buffer time-shared across phases -> 4 blocks/CU resident.
// ---------------------------------------------------------------------------
__global__ __launch_bounds__(256, 4) void attn_kernel(
    const float* __restrict__ query, const float* __restrict__ key,
    const float* __restrict__ drop_u, const bf16_t* __restrict__ vT,
    float* __restrict__ out)
{
  // phase A: K slabs (2 x 32 rows, double-buffered)
  // middle : P (64 q-rows x 256 k)
  // phase B: vT slabs (2 x 32 rows) -- safe: every wave caches its 16 P-rows
  //          in pf[] registers before the overlay barrier.
  __shared__ bf16_t KP[64 * LDSP];

  const int pidx = blockIdx.x;
  const int xcd  = pidx & 7;
  const int jj   = pidx >> 3;
  const int qt   = jj & 3;
  const int b    = xcd + ((jj >> 2) << 3);

  const int t    = threadIdx.x;
  const int w    = t >> 6;
  const int lane = t & 63;
  const int lid  = lane & 15;
  const int quad = lane >> 4;
  const int q0   = qt * 64 + w * 16;

  const float* Qb = query + (size_t)b * (SDIM * SDIM);
  const float* Kb = key   + (size_t)b * (SDIM * SDIM);

  // Issue K slab-0 loads first.
  float4 kr[8];
  #pragma unroll
  for (int p2 = 0; p2 < 8; ++p2)
    kr[p2] = *(const float4*)(Kb + (p2 * 4 + w) * SDIM + lane * 4);

  // Q fragments (A-layout: row = q0+lid, k = d*32 + quad*8 + j).
  bf16x8 qf[8];
  #pragma unroll
  for (int d = 0; d < 8; ++d) {
    const float* p = Qb + (q0 + lid) * SDIM + d * 32 + quad * 8;
    float4 a = *(const float4*)(p);
    float4 c = *(const float4*)(p + 4);
    qf[d] = cvt8(a, c);
  }

  // Write slab 0 into KP buffer 0.
  #pragma unroll
  for (int p2 = 0; p2 < 8; ++p2)
    *(bf16x4*)(&KP[(p2 * 4 + w) * LDSP + lane * 4]) = cvt4(kr[p2]);

  f32x4 sacc[16];
  #pragma unroll
  for (int n = 0; n < 16; ++n) sacc[n] = (f32x4){0.f, 0.f, 0.f, 0.f};

  // Phase A: pipelined over 8 slabs of 32 key rows.
  #pragma unroll
  for (int s = 0; s < 8; ++s) {
    if (s < 7) {
      #pragma unroll
      for (int p2 = 0; p2 < 8; ++p2)
        kr[p2] = *(const float4*)(Kb + ((s + 1) * 32 + p2 * 4 + w) * SDIM + lane * 4);
    }
    bar_lds();
    const int rb = (s & 1) * 32;
    #pragma unroll
    for (int n4 = 0; n4 < 2; ++n4) {
      const int n = s * 2 + n4;
      #pragma unroll
      for (int d = 0; d < 8; ++d) {
        bf16x8 bfr = *(const bf16x8*)(&KP[(rb + n4 * 16 + lid) * LDSP + d * 32 + quad * 8]);
        sacc[n] = __builtin_amdgcn_mfma_f32_16x16x32_bf16(qf[d], bfr, sacc[n], 0, 0, 0);
      }
    }
    if (s < 7) {
      const int wb = ((s + 1) & 1) * 32;
      #pragma unroll
      for (int p2 = 0; p2 < 8; ++p2)
        *(bf16x4*)(&KP[(wb + p2 * 4 + w) * LDSP + lane * 4]) = cvt4(kr[p2]);
    }
  }
  bar_lds();  // phase A reads done; KP free for P

  // Softmax per q-row (C-layout: q = quad*4+j, key = n*16+lid).
  #pragma unroll
  for (int j = 0; j < 4; ++j) {
    float mx = sacc[0][j];
    #pragma unroll
    for (int n = 1; n < 16; ++n) mx = fmaxf(mx, sacc[n][j]);
    #pragma unroll
    for (int off = 8; off >= 1; off >>= 1) mx = fmaxf(mx, __shfl_xor(mx, off, 64));
    float sum = 0.f;
    #pragma unroll
    for (int n = 0; n < 16; ++n) {
      float e = __expf((sacc[n][j] - mx) * 0.0625f);
      sacc[n][j] = e;
      sum += e;
    }
    #pragma unroll
    for (int off = 8; off >= 1; off >>= 1) sum += __shfl_xor(sum, off, 64);
    float inv = 1.0f / sum;
    #pragma unroll
    for (int n = 0; n < 16; ++n) sacc[n][j] *= inv;
  }

  // Write P (pre-dropout) to KP rows = q-within-tile.
  #pragma unroll
  for (int n = 0; n < 16; ++n) {
    #pragma unroll
    for (int j = 0; j < 4; ++j)
      KP[(w * 16 + quad * 4 + j) * LDSP + n * 16 + lid] = (bf16_t)sacc[n][j];
  }
  bar_lds();

  // Cache P fragments (B-layout: q-row = w*16+lid, k = k0*32 + quad*8 + j),
  // then apply dropout in-register: drop_u is read directly in this layout
  // (per lane 2xfloat4 per k0; the k0 loop consumes full 128B lines).
  bf16x8 pf[8];
  #pragma unroll
  for (int k0 = 0; k0 < 8; ++k0)
    pf[k0] = *(const bf16x8*)(&KP[(w * 16 + lid) * LDSP + k0 * 32 + quad * 8]);

  {
    const float* Ub = drop_u + (size_t)b * (SDIM * SDIM) + (size_t)(q0 + lid) * SDIM + quad * 8;
    const float rs = 1.0f / 0.9f;
    #pragma unroll
    for (int k0 = 0; k0 < 8; ++k0) {
      float4 u0 = *(const float4*)(Ub + k0 * 32);
      float4 u1 = *(const float4*)(Ub + k0 * 32 + 4);
      pf[k0][0] = (u0.x >= 0.1f) ? (bf16_t)((float)pf[k0][0] * rs) : (bf16_t)0.f;
      pf[k0][1] = (u0.y >= 0.1f) ? (bf16_t)((float)pf[k0][1] * rs) : (bf16_t)0.f;
      pf[k0][2] = (u0.z >= 0.1f) ? (bf16_t)((float)pf[k0][2] * rs) : (bf16_t)0.f;
      pf[k0][3] = (u0.w >= 0.1f) ? (bf16_t)((float)pf[k0][3] * rs) : (bf16_t)0.f;
      pf[k0][4] = (u1.x >= 0.1f) ? (bf16_t)((float)pf[k0][4] * rs) : (bf16_t)0.f;
      pf[k0][5] = (u1.y >= 0.1f) ? (bf16_t)((float)pf[k0][5] * rs) : (bf16_t)0.f;
      pf[k0][6] = (u1.z >= 0.1f) ? (bf16_t)((float)pf[k0][6] * rs) : (bf16_t)0.f;
      pf[k0][7] = (u1.w >= 0.1f) ? (bf16_t)((float)pf[k0][7] * rs) : (bf16_t)0.f;
    }
  }

  // Phase B prologue: issue vT slab-0 loads (regs only), then overlay barrier.
  const bf16_t* vTb = vT + (size_t)b * (SDIM * SDIM);
  float* outbp = out + (size_t)b * (SDIM * SDIM);

  bf16x8 tr[4];
  #pragma unroll
  for (int p3 = 0; p3 < 4; ++p3)
    tr[p3] = *(const bf16x8*)(vTb + (p3 * 8 + (t >> 5)) * SDIM + (t & 31) * 8);

  bar_lds();  // all pf reads of KP complete; KP free for vT slabs

  #pragma unroll
  for (int p3 = 0; p3 < 4; ++p3)
    *(bf16x8*)(&KP[(p3 * 8 + (t >> 5)) * LDSP + (t & 31) * 8]) = tr[p3];

  // Phase B: 8 slabs of 32 vT D-rows, double-buffered in KP halves.
  // out^T[D][q] = vT * P^T; per-slab streaming stores.
  #pragma unroll
  for (int s = 0; s < 8; ++s) {
    if (s < 7) {
      #pragma unroll
      for (int p3 = 0; p3 < 4; ++p3)
        tr[p3] = *(const bf16x8*)(vTb + ((s + 1) * 32 + p3 * 8 + (t >> 5)) * SDIM + (t & 31) * 8);
    }
    bar_lds();  // buffer s&1 ready; prior readers of buffer (s+1)&1 done
    const int rb = (s & 1) * 32;
    f32x4 o0 = (f32x4){0.f, 0.f, 0.f, 0.f};
    f32x4 o1 = (f32x4){0.f, 0.f, 0.f, 0.f};
    #pragma unroll
    for (int k0 = 0; k0 < 8; ++k0) {
      bf16x8 a0 = *(const bf16x8*)(&KP[(rb + lid) * LDSP + k0 * 32 + quad * 8]);
      bf16x8 a1 = *(const bf16x8*)(&KP[(rb + 16 + lid) * LDSP + k0 * 32 + quad * 8]);
      o0 = __builtin_amdgcn_mfma_f32_16x16x32_bf16(a0, pf[k0], o0, 0, 0, 0);
      o1 = __builtin_amdgcn_mfma_f32_16x16x32_bf16(a1, pf[k0], o1, 0, 0, 0);
    }
    if (s < 7) {
      const int wb = ((s + 1) & 1) * 32;
      #pragma unroll
      for (int p3 = 0; p3 < 4; ++p3)
        *(bf16x8*)(&KP[(wb + p3 * 8 + (t >> 5)) * LDSP + (t & 31) * 8]) = tr[p3];
    }
    #pragma unroll
    for (int j = 0; j < 4; ++j) {
      outbp[(s * 32 + quad * 4 + j) * SDIM + q0 + lid] = o0[j];
      outbp[(s * 32 + 16 + quad * 4 + j) * SDIM + q0 + lid] = o1[j];
    }
  }
}

extern "C" void kernel_launch(void* const* d_in, const int* in_sizes, int n_in,
                              void* d_out, int out_size, void* d_ws, size_t ws_size,
                              hipStream_t stream) {
  (void)in_sizes; (void)n_in; (void)out_size; (void)ws_size;
  const float* query    = (const float*)d_in[0];
  const float* key      = (const float*)d_in[1];
  const float* value    = (const float*)d_in[2];
  const float* drop_u   = (const float*)d_in[3];
  // d_in[4] = qk_bias: softmax-invariant -> skipped.
  const float* v_weight = (const float*)d_in[5];
  const float* v_bias   = (const float*)d_in[6];
  float* out = (float*)d_out;
  bf16_t* vT = (bf16_t*)d_ws;  // 33,554,432 bytes of workspace

  vproj_kernel<<<dim3(1024), dim3(256), 0, stream>>>(value, v_weight, v_bias, vT);
  attn_kernel<<<dim3(1024), dim3(256), 0, stream>>>(query, key, drop_u, vT, out);
}